// Round 5
// baseline (467.810 us; speedup 1.0000x reference)
//
#include <hip/hip_runtime.h>

// MultiHeadAttention: B=4, S=4096, D=256 (single head, fp32 in/out)
// cvt -> QKV GEMM (M-blocked, V key-bitswapped) -> 4-wave NQ=2 flash attention
// (fragment-order LDS, conflict-free, defer-max, split-K) -> combine -> out-proj

#define LOG2E 1.44269504088896340736f
#define THR 6.0f

typedef __attribute__((ext_vector_type(8)))  short short8;
typedef __attribute__((ext_vector_type(4)))  short short4v;
typedef __attribute__((ext_vector_type(4)))  float f32x4;
typedef __attribute__((ext_vector_type(16))) float f32x16;
typedef __attribute__((ext_vector_type(4)))  float float4v;
typedef __attribute__((ext_vector_type(2)))  float float2v;

static constexpr int BB = 4, SS = 4096, DD = 256;
static constexpr int KSPLIT = 4;

// ws element offsets (shorts)
static constexpr size_t OFF_W1  = 0;
static constexpr size_t OFF_W2  = 196608;
static constexpr size_t OFF_Q   = 262144;
static constexpr size_t OFF_K   = 4456448;
static constexpr size_t OFF_VT  = 8650752;                // [B][D][Sperm]
static constexpr size_t OFF_XB  = 12845056;               // x bf16; reused as VAL
static constexpr size_t OFF_VAL = 12845056;
static constexpr size_t OFF_OP  = 17039360;               // partial O bf16
static constexpr size_t OFF_ML  = 17039360 + (size_t)KSPLIT * BB * SS * DD;
static constexpr size_t WS_NEED_SPLIT = (OFF_ML + (size_t)BB * SS * KSPLIT * 2) * 2;

__device__ __forceinline__ short f2bf(float f) {
    union { float f; unsigned u; } v; v.f = f;
    unsigned u = v.u;
    u += 0x7fffu + ((u >> 16) & 1u);
    return (short)(u >> 16);
}
__device__ __forceinline__ float bf2f(short s) {
    union { unsigned u; float f; } v; v.u = ((unsigned)(unsigned short)s) << 16;
    return v.f;
}
__device__ __forceinline__ void gload_lds16(const void* g, void* l) {
    __builtin_amdgcn_global_load_lds(
        (const __attribute__((address_space(1))) unsigned int*)g,
        (__attribute__((address_space(3))) unsigned int*)l, 16, 0, 0);
}

// ---------------- fp32 -> bf16 convert ----------------
__global__ __launch_bounds__(256) void cvt_all(
    const float* __restrict__ x, const float* __restrict__ w1,
    const float* __restrict__ w2, short* __restrict__ xb,
    short* __restrict__ w1b, short* __restrict__ w2b)
{
    const int n_x = (BB * SS * DD) / 4;
    const int n_1 = (3 * DD * DD) / 4;
    const int n_2 = (DD * DD) / 4;
    int i = blockIdx.x * 256 + threadIdx.x;
    if (i >= n_x + n_1 + n_2) return;
    const float* src; short* dst; int off;
    if (i < n_x)            { src = x;  dst = xb;  off = i; }
    else if (i < n_x + n_1) { src = w1; dst = w1b; off = i - n_x; }
    else                    { src = w2; dst = w2b; off = i - n_x - n_1; }
    float4v v = *(const float4v*)(src + 4 * (size_t)off);
    short4v o;
    o[0] = f2bf(v[0]); o[1] = f2bf(v[1]); o[2] = f2bf(v[2]); o[3] = f2bf(v[3]);
    *(short4v*)(dst + 4 * (size_t)off) = o;
}

// ---------------- QKV projection (M-blocked x2) ----------------
__global__ __launch_bounds__(256) void qkv_gemm(
    const short* __restrict__ xb, const short* __restrict__ wb,
    const float* __restrict__ bias,
    short* __restrict__ Qw, short* __restrict__ Kw, short* __restrict__ Vt)
{
    const int lane = threadIdx.x & 63;
    const int w    = threadIdx.x >> 6;
    const int ln = lane & 15, lg = lane >> 4;
    const int mbase = blockIdx.x * 128 + w * 32;
    const int nbase = blockIdx.y * 64;

    f32x4 acc[2][4] = {};
    const short* arow0 = xb + (size_t)(mbase + ln) * DD + 8 * lg;
    const short* arow1 = arow0 + 16 * DD;
#pragma unroll
    for (int kk = 0; kk < 8; ++kk) {
        short8 a0 = *(const short8*)(arow0 + 32 * kk);
        short8 a1 = *(const short8*)(arow1 + 32 * kk);
#pragma unroll
        for (int nt = 0; nt < 4; ++nt) {
            short8 bf = *(const short8*)(wb + (size_t)(nbase + 16 * nt + ln) * DD + 32 * kk + 8 * lg);
            acc[0][nt] = __builtin_amdgcn_mfma_f32_16x16x32_bf16(a0, bf, acc[0][nt], 0, 0, 0);
            acc[1][nt] = __builtin_amdgcn_mfma_f32_16x16x32_bf16(a1, bf, acc[1][nt], 0, 0, 0);
        }
    }
#pragma unroll
    for (int mt = 0; mt < 2; ++mt) {
#pragma unroll
        for (int nt = 0; nt < 4; ++nt) {
            const int e = nbase + 16 * nt + ln;
            const float bv = bias[e];
            const int srow0 = mbase + mt * 16 + 4 * lg;
            const int b   = srow0 >> 12;
            const int si0 = srow0 & 4095;
            if (e < 256) {
#pragma unroll
                for (int r = 0; r < 4; ++r) {
                    float v = (acc[mt][nt][r] + bv) * 0.0625f;
                    Qw[((size_t)b * SS + si0 + r) * DD + e] = f2bf(v);
                }
            } else if (e < 512) {
#pragma unroll
                for (int r = 0; r < 4; ++r)
                    Kw[((size_t)b * SS + si0 + r) * DD + (e - 256)] = f2bf(acc[mt][nt][r] + bv);
            } else {
                short4v st;
#pragma unroll
                for (int r = 0; r < 4; ++r) st[r] = f2bf(acc[mt][nt][r] + bv);
                const int sp = (si0 & ~12) | ((si0 & 4) << 1) | ((si0 & 8) >> 1);
                *(short4v*)(Vt + ((size_t)b * DD + (e - 512)) * SS + sp) = st;
            }
        }
    }
}

// ---------------- 4-wave NQ=2 split-K flash attention ----------------
// Block: 256 thr = 4 waves, each wave 64 q-rows (2 q-tiles of 32). KVBLK=64.
// LDS = fragment order (1KB/fragment, lane l owns [f*1024+l*16,+16)).
// Each K/V fragment ds_read feeds 2 MFMAs (one per q-tile) -> LDS traffic/row halved.
template<int KSP>
__global__ __launch_bounds__(256, 1) void attn(
    const short* __restrict__ Qw, const short* __restrict__ Kw,
    const short* __restrict__ Vt, short* __restrict__ Opart,
    float* __restrict__ Ml, short* __restrict__ Val)
{
    constexpr int KCHUNK = SS / KSP;
    constexpr int NKB = KCHUNK / 64;
    extern __shared__ __align__(128) char smem[];   // [K0|K1|V0|V1] 32KB each

    const int id = blockIdx.x;
    const int combo = id % (KSP * BB);
    const int qb    = id / (KSP * BB);
    const int ks = combo % KSP;
    const int b  = combo / KSP;
    const int t = threadIdx.x;
    const int lane = t & 63, w = t >> 6;
    const int lr = lane & 31, hi = lane >> 5;
    const int q0 = qb * 256 + w * 64;
    const int kbeg = ks * KCHUNK;

    // Q fragments: B-operand, lane holds Q[q0+t2*32+lr][16c+8hi .. +7]
    short8 qf[2][16];
#pragma unroll
    for (int t2 = 0; t2 < 2; ++t2) {
        const short* Qp = Qw + ((size_t)b * SS + q0 + t2 * 32 + lr) * DD + 8 * hi;
#pragma unroll
        for (int c = 0; c < 16; ++c) qf[t2][c] = *(const short8*)(Qp + 16 * c);
    }

    f32x16 o_acc[2][8] = {};
    float m_run[2] = { -1e30f, -1e30f };
    float l_part[2] = { 0.f, 0.f };

    const char* Kg0 = (const char*)(Kw + ((size_t)b * SS + kbeg) * DD);
    const char* Vg0 = (const char*)(Vt + (size_t)b * DD * SS) + 2 * kbeg;

    const size_t koff = (size_t)lr * 512 + hi * 16;
    const size_t voff = (size_t)lr * 8192 + hi * 16;

    auto stage = [&](int buf, int kb) {
        char* kd = smem + buf * 32768;
        char* vd = smem + 65536 + buf * 32768;
        const char* kg = Kg0 + (size_t)kb * 32768;
        const char* vg = Vg0 + (size_t)kb * 128;
#pragma unroll
        for (int i = 0; i < 8; ++i) {
            const int f = w * 8 + i;                       // 0..31
            const int kt = f >> 4, c = f & 15;
            gload_lds16(kg + (size_t)kt * 16384 + koff + c * 32, kd + f * 1024);
            const int s = f >> 3, dt = f & 7;
            gload_lds16(vg + (size_t)dt * 262144 + voff + s * 32, vd + f * 1024);
        }
    };

    stage(0, 0);
    __syncthreads();
    int cur = 0;

    for (int kb = 0; kb < NKB; ++kb) {
        if (kb + 1 < NKB) stage(cur ^ 1, kb + 1);

        const char* myK = smem + cur * 32768 + lane * 16;
        const char* myV = smem + 65536 + cur * 32768 + lane * 16;

        // QK^T: S^T[key][q], each kf feeds both q-tiles
        f32x16 sacc[2][2] = {};
        __builtin_amdgcn_s_setprio(1);
#pragma unroll
        for (int c = 0; c < 16; ++c) {
#pragma unroll
            for (int kt = 0; kt < 2; ++kt) {
                short8 kf = *(const short8*)(myK + (kt * 16 + c) * 1024);
                sacc[0][kt] = __builtin_amdgcn_mfma_f32_32x32x16_bf16(kf, qf[0][c], sacc[0][kt], 0, 0, 0);
                sacc[1][kt] = __builtin_amdgcn_mfma_f32_32x32x16_bf16(kf, qf[1][c], sacc[1][kt], 0, 0, 0);
            }
        }
        __builtin_amdgcn_s_setprio(0);

        // online softmax with defer-max, per q-tile
#pragma unroll
        for (int t2 = 0; t2 < 2; ++t2) {
            float pm = -1e30f;
#pragma unroll
            for (int kt = 0; kt < 2; ++kt)
#pragma unroll
                for (int r = 0; r < 16; ++r) pm = fmaxf(pm, sacc[t2][kt][r]);
            pm = fmaxf(pm, __shfl_xor(pm, 32));
            if (__any(pm > m_run[t2] + THR)) {
                const float mnew = fmaxf(m_run[t2], pm);
                const float corr = exp2f((m_run[t2] - mnew) * LOG2E);
                m_run[t2] = mnew;
                l_part[t2] *= corr;
#pragma unroll
                for (int dt = 0; dt < 8; ++dt)
#pragma unroll
                    for (int r = 0; r < 16; ++r) o_acc[t2][dt][r] *= corr;
            }
            const float mref = m_run[t2];
            float ps0 = 0.f, ps1 = 0.f;
#pragma unroll
            for (int kt = 0; kt < 2; ++kt)
#pragma unroll
                for (int r = 0; r < 16; ++r) {
                    float p = exp2f((sacc[t2][kt][r] - mref) * LOG2E);
                    if (r & 1) ps1 += p; else ps0 += p;
                    sacc[t2][kt][r] = p;
                }
            l_part[t2] += ps0 + ps1;
        }

        // PV: each vf feeds both q-tiles
#pragma unroll
        for (int s = 0; s < 4; ++s) {
            short8 pb0, pb1;
#pragma unroll
            for (int j = 0; j < 8; ++j) {
                const int r = (j & 3) + 4 * (j >> 2) + 8 * (s & 1);
                pb0[j] = f2bf(sacc[0][s >> 1][r]);
                pb1[j] = f2bf(sacc[1][s >> 1][r]);
            }
            __builtin_amdgcn_s_setprio(1);
#pragma unroll
            for (int dt = 0; dt < 8; ++dt) {
                short8 vf = *(const short8*)(myV + (s * 8 + dt) * 1024);
                o_acc[0][dt] = __builtin_amdgcn_mfma_f32_32x32x16_bf16(vf, pb0, o_acc[0][dt], 0, 0, 0);
                o_acc[1][dt] = __builtin_amdgcn_mfma_f32_32x32x16_bf16(vf, pb1, o_acc[1][dt], 0, 0, 0);
            }
            __builtin_amdgcn_s_setprio(0);
        }
        __syncthreads();
        cur ^= 1;
    }

#pragma unroll
    for (int t2 = 0; t2 < 2; ++t2) {
        float lt = l_part[t2] + __shfl_xor(l_part[t2], 32);
        const float inv = 1.0f / lt;
        const size_t row = (size_t)b * SS + q0 + t2 * 32 + lr;
        short* vo = (KSP == 1 ? Val : Opart + (size_t)ks * (BB * SS) * DD)
                    + row * DD;
#pragma unroll
        for (int dt = 0; dt < 8; ++dt)
#pragma unroll
            for (int g = 0; g < 4; ++g) {
                short4v st;
#pragma unroll
                for (int i = 0; i < 4; ++i) st[i] = f2bf(o_acc[t2][dt][4 * g + i] * inv);
                *(short4v*)(vo + dt * 32 + 8 * g + 4 * hi) = st;
            }
        if (KSP > 1 && hi == 0) {
            float2v ml; ml[0] = m_run[t2]; ml[1] = lt;
            *(float2v*)(Ml + (row * KSP + ks) * 2) = ml;
        }
    }
}

// ---------------- split combine (vectorized x4) ----------------
__global__ __launch_bounds__(256) void combine(
    const short* __restrict__ Opart, const float* __restrict__ Ml,
    short* __restrict__ Val)
{
    const int idx = blockIdx.x * 256 + threadIdx.x;   // one 4-elem group
    const int row = idx >> 6;
    const int d4 = (idx & 63) * 4;
    float m[KSPLIT], l[KSPLIT];
    float M = -1e30f;
#pragma unroll
    for (int i = 0; i < KSPLIT; ++i) {
        float2v v = *(const float2v*)(Ml + ((size_t)row * KSPLIT + i) * 2);
        m[i] = v[0]; l[i] = v[1];
        M = fmaxf(M, m[i]);
    }
    float wsum = 0.f;
    f32x4 acc = {};
#pragma unroll
    for (int i = 0; i < KSPLIT; ++i) {
        float wgt = l[i] * exp2f((m[i] - M) * LOG2E);
        wsum += wgt;
        short4v v = *(const short4v*)(Opart + (size_t)i * (BB * SS * DD) + (size_t)row * DD + d4);
#pragma unroll
        for (int j = 0; j < 4; ++j) acc[j] += wgt * bf2f(v[j]);
    }
    const float inv = 1.0f / wsum;
    short4v st;
#pragma unroll
    for (int j = 0; j < 4; ++j) st[j] = f2bf(acc[j] * inv);
    *(short4v*)(Val + (size_t)row * DD + d4) = st;
}

// ---------------- out projection (M-blocked x2) -> fp32 ----------------
__global__ __launch_bounds__(256) void oproj_gemm(
    const short* __restrict__ vb, const short* __restrict__ wb,
    const float* __restrict__ bias, float* __restrict__ out)
{
    const int lane = threadIdx.x & 63;
    const int w    = threadIdx.x >> 6;
    const int ln = lane & 15, lg = lane >> 4;
    const int mbase = blockIdx.x * 128 + w * 32;
    const int nbase = blockIdx.y * 64;

    f32x4 acc[2][4] = {};
    const short* arow0 = vb + (size_t)(mbase + ln) * DD + 8 * lg;
    const short* arow1 = arow0 + 16 * DD;
#pragma unroll
    for (int kk = 0; kk < 8; ++kk) {
        short8 a0 = *(const short8*)(arow0 + 32 * kk);
        short8 a1 = *(const short8*)(arow1 + 32 * kk);
#pragma unroll
        for (int nt = 0; nt < 4; ++nt) {
            short8 bf = *(const short8*)(wb + (size_t)(nbase + 16 * nt + ln) * DD + 32 * kk + 8 * lg);
            acc[0][nt] = __builtin_amdgcn_mfma_f32_16x16x32_bf16(a0, bf, acc[0][nt], 0, 0, 0);
            acc[1][nt] = __builtin_amdgcn_mfma_f32_16x16x32_bf16(a1, bf, acc[1][nt], 0, 0, 0);
        }
    }
#pragma unroll
    for (int mt = 0; mt < 2; ++mt)
#pragma unroll
        for (int nt = 0; nt < 4; ++nt) {
            const int e = nbase + 16 * nt + ln;
            const float bv = bias[e];
#pragma unroll
            for (int r = 0; r < 4; ++r)
                out[(size_t)(mbase + mt * 16 + 4 * lg + r) * DD + e] = acc[mt][nt][r] + bv;
        }
}

extern "C" void kernel_launch(void* const* d_in, const int* in_sizes, int n_in,
                              void* d_out, int out_size, void* d_ws, size_t ws_size,
                              hipStream_t stream) {
    const float* x    = (const float*)d_in[0];
    const float* Wqkv = (const float*)d_in[1];
    const float* bqkv = (const float*)d_in[2];
    const float* Wo   = (const float*)d_in[3];
    const float* bo   = (const float*)d_in[4];
    float* out = (float*)d_out;
    short* ws  = (short*)d_ws;

    short* w1b = ws + OFF_W1;
    short* w2b = ws + OFF_W2;
    short* Qw  = ws + OFF_Q;
    short* Kw  = ws + OFF_K;
    short* Vt  = ws + OFF_VT;
    short* xb  = ws + OFF_XB;
    short* Val = ws + OFF_VAL;
    short* Opart = ws + OFF_OP;
    float* Ml  = (float*)(ws + OFF_ML);

    cvt_all<<<4352, 256, 0, stream>>>(x, Wqkv, Wo, xb, w1b, w2b);
    qkv_gemm<<<dim3(128, 12), 256, 0, stream>>>(xb, w1b, bqkv, Qw, Kw, Vt);

    constexpr size_t SMEM = 131072;
    if (ws_size >= WS_NEED_SPLIT) {
        (void)hipFuncSetAttribute((const void*)attn<KSPLIT>,
                                  hipFuncAttributeMaxDynamicSharedMemorySize, SMEM);
        attn<KSPLIT><<<16 * KSPLIT * BB, 256, SMEM, stream>>>(Qw, Kw, Vt, Opart, Ml, nullptr);
        combine<<<4096, 256, 0, stream>>>(Opart, Ml, Val);
    } else {
        (void)hipFuncSetAttribute((const void*)attn<1>,
                                  hipFuncAttributeMaxDynamicSharedMemorySize, SMEM);
        attn<1><<<16 * BB, 256, SMEM, stream>>>(Qw, Kw, Vt, nullptr, nullptr, Val);
    }
    oproj_gemm<<<dim3(128, 4), 256, 0, stream>>>(Val, w2b, bo, out);
}

// Round 6
// 154.434 us; speedup vs baseline: 3.0292x; 3.0292x over previous
//
#include <hip/hip_runtime.h>

// MultiHeadAttention: B=4, S=4096, D=256 (single head, fp32 in/out)
// cvt -> QKV GEMM (M-blocked, V key-bitswapped) -> 8-wave 32q flash attention
// (fragment-order LDS, KVBLK=32 triple-buffer, counted vmcnt, defer-max,
//  cvt_pk P-pack, split-K) -> combine -> out-proj

#define LOG2E 1.44269504088896340736f
#define THR 6.0f

typedef __attribute__((ext_vector_type(8)))  short short8;
typedef __attribute__((ext_vector_type(4)))  short short4v;
typedef __attribute__((ext_vector_type(4)))  float f32x4;
typedef __attribute__((ext_vector_type(16))) float f32x16;
typedef __attribute__((ext_vector_type(4)))  float float4v;
typedef __attribute__((ext_vector_type(2)))  float float2v;

static constexpr int BB = 4, SS = 4096, DD = 256;
static constexpr int KSPLIT = 4;

// ws element offsets (shorts)
static constexpr size_t OFF_W1  = 0;
static constexpr size_t OFF_W2  = 196608;
static constexpr size_t OFF_Q   = 262144;
static constexpr size_t OFF_K   = 4456448;
static constexpr size_t OFF_VT  = 8650752;                // [B][D][Sperm]
static constexpr size_t OFF_XB  = 12845056;               // x bf16; reused as VAL
static constexpr size_t OFF_VAL = 12845056;
static constexpr size_t OFF_OP  = 17039360;               // partial O bf16
static constexpr size_t OFF_ML  = 17039360 + (size_t)KSPLIT * BB * SS * DD;
static constexpr size_t WS_NEED_SPLIT = (OFF_ML + (size_t)BB * SS * KSPLIT * 2) * 2;

__device__ __forceinline__ short f2bf(float f) {
    union { float f; unsigned u; } v; v.f = f;
    unsigned u = v.u;
    u += 0x7fffu + ((u >> 16) & 1u);
    return (short)(u >> 16);
}
__device__ __forceinline__ float bf2f(short s) {
    union { unsigned u; float f; } v; v.u = ((unsigned)(unsigned short)s) << 16;
    return v.f;
}
__device__ __forceinline__ void gload_lds16(const void* g, void* l) {
    __builtin_amdgcn_global_load_lds(
        (const __attribute__((address_space(1))) unsigned int*)g,
        (__attribute__((address_space(3))) unsigned int*)l, 16, 0, 0);
}

// ---------------- fp32 -> bf16 convert ----------------
__global__ __launch_bounds__(256) void cvt_all(
    const float* __restrict__ x, const float* __restrict__ w1,
    const float* __restrict__ w2, short* __restrict__ xb,
    short* __restrict__ w1b, short* __restrict__ w2b)
{
    const int n_x = (BB * SS * DD) / 4;
    const int n_1 = (3 * DD * DD) / 4;
    const int n_2 = (DD * DD) / 4;
    int i = blockIdx.x * 256 + threadIdx.x;
    if (i >= n_x + n_1 + n_2) return;
    const float* src; short* dst; int off;
    if (i < n_x)            { src = x;  dst = xb;  off = i; }
    else if (i < n_x + n_1) { src = w1; dst = w1b; off = i - n_x; }
    else                    { src = w2; dst = w2b; off = i - n_x - n_1; }
    float4v v = *(const float4v*)(src + 4 * (size_t)off);
    short4v o;
    o[0] = f2bf(v[0]); o[1] = f2bf(v[1]); o[2] = f2bf(v[2]); o[3] = f2bf(v[3]);
    *(short4v*)(dst + 4 * (size_t)off) = o;
}

// ---------------- QKV projection (M-blocked x2) ----------------
__global__ __launch_bounds__(256) void qkv_gemm(
    const short* __restrict__ xb, const short* __restrict__ wb,
    const float* __restrict__ bias,
    short* __restrict__ Qw, short* __restrict__ Kw, short* __restrict__ Vt)
{
    const int lane = threadIdx.x & 63;
    const int w    = threadIdx.x >> 6;
    const int ln = lane & 15, lg = lane >> 4;
    const int mbase = blockIdx.x * 128 + w * 32;
    const int nbase = blockIdx.y * 64;

    f32x4 acc[2][4] = {};
    const short* arow0 = xb + (size_t)(mbase + ln) * DD + 8 * lg;
    const short* arow1 = arow0 + 16 * DD;
#pragma unroll
    for (int kk = 0; kk < 8; ++kk) {
        short8 a0 = *(const short8*)(arow0 + 32 * kk);
        short8 a1 = *(const short8*)(arow1 + 32 * kk);
#pragma unroll
        for (int nt = 0; nt < 4; ++nt) {
            short8 bf = *(const short8*)(wb + (size_t)(nbase + 16 * nt + ln) * DD + 32 * kk + 8 * lg);
            acc[0][nt] = __builtin_amdgcn_mfma_f32_16x16x32_bf16(a0, bf, acc[0][nt], 0, 0, 0);
            acc[1][nt] = __builtin_amdgcn_mfma_f32_16x16x32_bf16(a1, bf, acc[1][nt], 0, 0, 0);
        }
    }
#pragma unroll
    for (int mt = 0; mt < 2; ++mt) {
#pragma unroll
        for (int nt = 0; nt < 4; ++nt) {
            const int e = nbase + 16 * nt + ln;
            const float bv = bias[e];
            const int srow0 = mbase + mt * 16 + 4 * lg;
            const int b   = srow0 >> 12;
            const int si0 = srow0 & 4095;
            if (e < 256) {
#pragma unroll
                for (int r = 0; r < 4; ++r) {
                    float v = (acc[mt][nt][r] + bv) * 0.0625f;
                    Qw[((size_t)b * SS + si0 + r) * DD + e] = f2bf(v);
                }
            } else if (e < 512) {
#pragma unroll
                for (int r = 0; r < 4; ++r)
                    Kw[((size_t)b * SS + si0 + r) * DD + (e - 256)] = f2bf(acc[mt][nt][r] + bv);
            } else {
                short4v st;
#pragma unroll
                for (int r = 0; r < 4; ++r) st[r] = f2bf(acc[mt][nt][r] + bv);
                const int sp = (si0 & ~12) | ((si0 & 4) << 1) | ((si0 & 8) >> 1);
                *(short4v*)(Vt + ((size_t)b * DD + (e - 512)) * SS + sp) = st;
            }
        }
    }
}

// ---------------- 8-wave split-K flash attention ----------------
// 512 thr = 8 waves x 32 q-rows. KVBLK=32, triple-buffered fragment-order LDS
// (1KB/fragment, lane l owns [f*1024+l*16,+16)): K frags c in [0,16),
// V frags s*8+dt in [0,16). Counted vmcnt(4) keeps next-next tile's stage
// loads in flight across the barrier (T3/T4). Defer-max (T13) skips O-rescale.
template<int KSP>
__global__ __launch_bounds__(512, 2) void attn(
    const short* __restrict__ Qw, const short* __restrict__ Kw,
    const short* __restrict__ Vt, short* __restrict__ Opart,
    float* __restrict__ Ml, short* __restrict__ Val)
{
    constexpr int KCHUNK = SS / KSP;
    constexpr int NKB = KCHUNK / 32;
    extern __shared__ __align__(128) char smem[];   // 3 x (K 16KB | V 16KB)

    const int id = blockIdx.x;
    const int combo = id % (KSP * BB);
    const int qb    = id / (KSP * BB);
    const int ks = combo % KSP;
    const int b  = combo / KSP;
    const int t = threadIdx.x;
    const int lane = t & 63, w = t >> 6;
    const int lr = lane & 31, hi = lane >> 5;
    const int q0 = qb * 256 + w * 32;
    const int kbeg = ks * KCHUNK;

    // Q fragments: B-operand, lane holds Q[q0+lr][16c+8hi .. +7]
    const short* Qp = Qw + ((size_t)b * SS + q0 + lr) * DD + 8 * hi;
    short8 qf[16];
#pragma unroll
    for (int c = 0; c < 16; ++c) qf[c] = *(const short8*)(Qp + 16 * c);

    f32x16 o_acc[8] = {};
    float m_run = -1e30f, l_part = 0.f;

    const char* Kg0 = (const char*)(Kw + ((size_t)b * SS + kbeg) * DD);
    const char* Vg0 = (const char*)(Vt + (size_t)b * DD * SS) + 2 * kbeg;

    // stage one 32-key tile (32 fragments; wave w stages f = w*4 .. w*4+3)
    auto stage = [&](int buf, int kb) {
        char* base = smem + buf * 32768;
        const char* kg = Kg0 + (size_t)kb * 16384;     // 32 keys * 512B
        const char* vg = Vg0 + (size_t)kb * 64;        // 32 keys * 2B per d-row
#pragma unroll
        for (int i = 0; i < 4; ++i) {
            const int f = w * 4 + i;                   // 0..31, wave-uniform
            if (f < 16) {
                gload_lds16(kg + (size_t)lr * 512 + f * 32 + hi * 16,
                            base + f * 1024);
            } else {
                const int g = f - 16, s = g >> 3, dt = g & 7;
                gload_lds16(vg + (size_t)(dt * 32 + lr) * 8192 + s * 32 + hi * 16,
                            base + 16384 + g * 1024);
            }
        }
    };

    stage(0, 0);
    stage(1, 1);
    asm volatile("s_waitcnt vmcnt(4)" ::: "memory");   // tile 0 landed (tile 1 flying)
    __builtin_amdgcn_s_barrier();

    int cur = 0;
    for (int kb = 0; kb < NKB; ++kb) {
        const int nx2 = (cur + 2 >= 3) ? cur - 1 : cur + 2;
        if (kb + 2 < NKB) stage(nx2, kb + 2);

        const char* myK = smem + cur * 32768 + lane * 16;
        const char* myV = smem + cur * 32768 + 16384 + lane * 16;

        // QK^T: S^T[key][q]
        f32x16 sacc = {};
        __builtin_amdgcn_s_setprio(1);
#pragma unroll
        for (int c = 0; c < 16; ++c) {
            short8 kf = *(const short8*)(myK + c * 1024);
            sacc = __builtin_amdgcn_mfma_f32_32x32x16_bf16(kf, qf[c], sacc, 0, 0, 0);
        }
        __builtin_amdgcn_s_setprio(0);

        // online softmax with defer-max (q col held by lanes l, l+32)
        float pm = sacc[0];
#pragma unroll
        for (int r = 1; r < 16; ++r) pm = fmaxf(pm, sacc[r]);
        pm = fmaxf(pm, __shfl_xor(pm, 32));
        if (__any(pm > m_run + THR)) {
            const float mnew = fmaxf(m_run, pm);
            const float corr = exp2f((m_run - mnew) * LOG2E);
            m_run = mnew;
            l_part *= corr;
#pragma unroll
            for (int dt = 0; dt < 8; ++dt)
#pragma unroll
                for (int r = 0; r < 16; ++r) o_acc[dt][r] *= corr;
        }
        const float mref = m_run;
        float ps0 = 0.f, ps1 = 0.f;
#pragma unroll
        for (int r = 0; r < 16; ++r) {
            float p = exp2f((sacc[r] - mref) * LOG2E);
            if (r & 1) ps1 += p; else ps0 += p;
            sacc[r] = p;
        }
        l_part += ps0 + ps1;

        // PV: O^T[d][q] += V^T[d][key] * P^T[key][q]
#pragma unroll
        for (int s = 0; s < 2; ++s) {
            union { short8 v; unsigned u[4]; } pb;
#pragma unroll
            for (int i = 0; i < 4; ++i)
                asm("v_cvt_pk_bf16_f32 %0, %1, %2"
                    : "=v"(pb.u[i])
                    : "v"(sacc[8 * s + 2 * i]), "v"(sacc[8 * s + 2 * i + 1]));
            __builtin_amdgcn_s_setprio(1);
#pragma unroll
            for (int dt = 0; dt < 8; ++dt) {
                short8 vf = *(const short8*)(myV + (s * 8 + dt) * 1024);
                o_acc[dt] = __builtin_amdgcn_mfma_f32_32x32x16_bf16(vf, pb.v, o_acc[dt], 0, 0, 0);
            }
            __builtin_amdgcn_s_setprio(0);
        }

        if (kb + 1 < NKB) {
            if (kb + 2 < NKB) asm volatile("s_waitcnt vmcnt(4)" ::: "memory");
            else              asm volatile("s_waitcnt vmcnt(0)" ::: "memory");
            __builtin_amdgcn_s_barrier();
        }
        cur = (cur + 1 >= 3) ? 0 : cur + 1;
    }

    float lt = l_part + __shfl_xor(l_part, 32);
    const float inv = 1.0f / lt;
    const size_t row = (size_t)b * SS + q0 + lr;
    short* vo = (KSP == 1 ? Val : Opart + (size_t)ks * (BB * SS) * DD) + row * DD;
#pragma unroll
    for (int dt = 0; dt < 8; ++dt)
#pragma unroll
        for (int g = 0; g < 4; ++g) {
            short4v st;
#pragma unroll
            for (int i = 0; i < 4; ++i) st[i] = f2bf(o_acc[dt][4 * g + i] * inv);
            *(short4v*)(vo + dt * 32 + 8 * g + 4 * hi) = st;
        }
    if (KSP > 1 && hi == 0) {
        float2v ml; ml[0] = m_run; ml[1] = lt;
        *(float2v*)(Ml + (row * KSP + ks) * 2) = ml;
    }
}

// ---------------- split combine (vectorized x4) ----------------
__global__ __launch_bounds__(256) void combine(
    const short* __restrict__ Opart, const float* __restrict__ Ml,
    short* __restrict__ Val)
{
    const int idx = blockIdx.x * 256 + threadIdx.x;   // one 4-elem group
    const int row = idx >> 6;
    const int d4 = (idx & 63) * 4;
    float m[KSPLIT], l[KSPLIT];
    float M = -1e30f;
#pragma unroll
    for (int i = 0; i < KSPLIT; ++i) {
        float2v v = *(const float2v*)(Ml + ((size_t)row * KSPLIT + i) * 2);
        m[i] = v[0]; l[i] = v[1];
        M = fmaxf(M, m[i]);
    }
    float wsum = 0.f;
    f32x4 acc = {};
#pragma unroll
    for (int i = 0; i < KSPLIT; ++i) {
        float wgt = l[i] * exp2f((m[i] - M) * LOG2E);
        wsum += wgt;
        short4v v = *(const short4v*)(Opart + (size_t)i * (BB * SS * DD) + (size_t)row * DD + d4);
#pragma unroll
        for (int j = 0; j < 4; ++j) acc[j] += wgt * bf2f(v[j]);
    }
    const float inv = 1.0f / wsum;
    short4v st;
#pragma unroll
    for (int j = 0; j < 4; ++j) st[j] = f2bf(acc[j] * inv);
    *(short4v*)(Val + (size_t)row * DD + d4) = st;
}

// ---------------- out projection (M-blocked x2) -> fp32 ----------------
__global__ __launch_bounds__(256) void oproj_gemm(
    const short* __restrict__ vb, const short* __restrict__ wb,
    const float* __restrict__ bias, float* __restrict__ out)
{
    const int lane = threadIdx.x & 63;
    const int w    = threadIdx.x >> 6;
    const int ln = lane & 15, lg = lane >> 4;
    const int mbase = blockIdx.x * 128 + w * 32;
    const int nbase = blockIdx.y * 64;

    f32x4 acc[2][4] = {};
    const short* arow0 = vb + (size_t)(mbase + ln) * DD + 8 * lg;
    const short* arow1 = arow0 + 16 * DD;
#pragma unroll
    for (int kk = 0; kk < 8; ++kk) {
        short8 a0 = *(const short8*)(arow0 + 32 * kk);
        short8 a1 = *(const short8*)(arow1 + 32 * kk);
#pragma unroll
        for (int nt = 0; nt < 4; ++nt) {
            short8 bf = *(const short8*)(wb + (size_t)(nbase + 16 * nt + ln) * DD + 32 * kk + 8 * lg);
            acc[0][nt] = __builtin_amdgcn_mfma_f32_16x16x32_bf16(a0, bf, acc[0][nt], 0, 0, 0);
            acc[1][nt] = __builtin_amdgcn_mfma_f32_16x16x32_bf16(a1, bf, acc[1][nt], 0, 0, 0);
        }
    }
#pragma unroll
    for (int mt = 0; mt < 2; ++mt)
#pragma unroll
        for (int nt = 0; nt < 4; ++nt) {
            const int e = nbase + 16 * nt + ln;
            const float bv = bias[e];
#pragma unroll
            for (int r = 0; r < 4; ++r)
                out[(size_t)(mbase + mt * 16 + 4 * lg + r) * DD + e] = acc[mt][nt][r] + bv;
        }
}

extern "C" void kernel_launch(void* const* d_in, const int* in_sizes, int n_in,
                              void* d_out, int out_size, void* d_ws, size_t ws_size,
                              hipStream_t stream) {
    const float* x    = (const float*)d_in[0];
    const float* Wqkv = (const float*)d_in[1];
    const float* bqkv = (const float*)d_in[2];
    const float* Wo   = (const float*)d_in[3];
    const float* bo   = (const float*)d_in[4];
    float* out = (float*)d_out;
    short* ws  = (short*)d_ws;

    short* w1b = ws + OFF_W1;
    short* w2b = ws + OFF_W2;
    short* Qw  = ws + OFF_Q;
    short* Kw  = ws + OFF_K;
    short* Vt  = ws + OFF_VT;
    short* xb  = ws + OFF_XB;
    short* Val = ws + OFF_VAL;
    short* Opart = ws + OFF_OP;
    float* Ml  = (float*)(ws + OFF_ML);

    cvt_all<<<4352, 256, 0, stream>>>(x, Wqkv, Wo, xb, w1b, w2b);
    qkv_gemm<<<dim3(128, 12), 256, 0, stream>>>(xb, w1b, bqkv, Qw, Kw, Vt);

    constexpr size_t SMEM = 98304;
    if (ws_size >= WS_NEED_SPLIT) {
        (void)hipFuncSetAttribute((const void*)attn<KSPLIT>,
                                  hipFuncAttributeMaxDynamicSharedMemorySize, SMEM);
        attn<KSPLIT><<<16 * KSPLIT * BB, 512, SMEM, stream>>>(Qw, Kw, Vt, Opart, Ml, nullptr);
        combine<<<4096, 256, 0, stream>>>(Opart, Ml, Val);
    } else {
        (void)hipFuncSetAttribute((const void*)attn<1>,
                                  hipFuncAttributeMaxDynamicSharedMemorySize, SMEM);
        attn<1><<<16 * BB, 512, SMEM, stream>>>(Qw, Kw, Vt, nullptr, nullptr, Val);
    }
    oproj_gemm<<<dim3(128, 4), 256, 0, stream>>>(Val, w2b, bo, out);
}